// Round 3
// baseline (2971.984 us; speedup 1.0000x reference)
//
#include <hip/hip_runtime.h>
#include <stdint.h>

#define BB 8
#define TTN 4096
#define CCH 32
#define KEEP_LT 6710887u     // keep iff (bits>>9) < this  <=> uniform < 0.8f

__device__ __forceinline__ uint32_t rotl32(uint32_t x, int r) {
    return (x << r) | (x >> (32 - r));
}

// threefry2x32, 20 rounds, key fixed to (0, 42) == jax.random.key(42)
__device__ __forceinline__ void threefry2x32_k042(uint32_t x0, uint32_t x1,
                                                  uint32_t& o0, uint32_t& o1) {
    const uint32_t k0 = 0u, k1 = 42u;
    const uint32_t k2 = 0u ^ 42u ^ 0x1BD11BDAu;
    x0 += k0; x1 += k1;
#define TFR(r) { x0 += x1; x1 = rotl32(x1, (r)); x1 ^= x0; }
    TFR(13) TFR(15) TFR(26) TFR(6)
    x0 += k1; x1 += k2 + 1u;
    TFR(17) TFR(29) TFR(16) TFR(24)
    x0 += k2; x1 += k0 + 2u;
    TFR(13) TFR(15) TFR(26) TFR(6)
    x0 += k0; x1 += k1 + 3u;
    TFR(17) TFR(29) TFR(16) TFR(24)
    x0 += k1; x1 += k2 + 4u;
    TFR(13) TFR(15) TFR(26) TFR(6)
    x0 += k2; x1 += k0 + 5u;
#undef TFR
    o0 = x0; o1 = x1;
}

// partitionable threefry: bits(i) = o0^o1 of threefry(key42, (0, i))
__device__ __forceinline__ uint32_t mask_bits(uint32_t idx) {
    uint32_t o0, o1; threefry2x32_k042(0u, idx, o0, o1); return o0 ^ o1;
}

// ---------------- projections: q = (x @ Wq^T) * 1/sqrt(32), k, v ----------------
__global__ __launch_bounds__(256) void proj_qkv(const float* __restrict__ x,
                                                const float* __restrict__ Wq,
                                                const float* __restrict__ Wk,
                                                const float* __restrict__ Wv,
                                                float* __restrict__ Q,
                                                float* __restrict__ K,
                                                float* __restrict__ V) {
    __shared__ float sW[3][CCH * CCH];
    const int tid = threadIdx.x;
    for (int i = tid; i < CCH * CCH; i += 256) {
        sW[0][i] = Wq[i]; sW[1][i] = Wk[i]; sW[2][i] = Wv[i];
    }
    __syncthreads();
    const int row = blockIdx.x * 256 + tid;     // b*T + t
    const float4* xp = reinterpret_cast<const float4*>(x + (size_t)row * CCH);
    float xr[CCH];
    #pragma unroll
    for (int i = 0; i < 8; ++i) {
        float4 t4 = xp[i];
        xr[4*i] = t4.x; xr[4*i+1] = t4.y; xr[4*i+2] = t4.z; xr[4*i+3] = t4.w;
    }
    const float scale = 0.17677669529663687f;   // 1/sqrt(32)
    for (int mtx = 0; mtx < 3; ++mtx) {
        float* op_base = (mtx == 0) ? Q : ((mtx == 1) ? K : V);
        float o[CCH];
        #pragma unroll
        for (int d = 0; d < CCH; ++d) {
            float s0 = 0.f, s1 = 0.f, s2 = 0.f, s3 = 0.f;
            #pragma unroll
            for (int c = 0; c < CCH; c += 4) {
                s0 += xr[c]   * sW[mtx][d*CCH + c];
                s1 += xr[c+1] * sW[mtx][d*CCH + c+1];
                s2 += xr[c+2] * sW[mtx][d*CCH + c+2];
                s3 += xr[c+3] * sW[mtx][d*CCH + c+3];
            }
            o[d] = (s0 + s1) + (s2 + s3);
            if (mtx == 0) o[d] *= scale;
        }
        float4* op = reinterpret_cast<float4*>(op_base + (size_t)row * CCH);
        #pragma unroll
        for (int i = 0; i < 8; ++i)
            op[i] = make_float4(o[4*i], o[4*i+1], o[4*i+2], o[4*i+3]);
    }
}

// merge partial (m2,l2,acc2) into (m,l,acc); no-op when l2==0 (avoids inf-inf NaN)
__device__ __forceinline__ void merge_partial(float& m, float& l, float* acc,
                                              float m2, float l2, const float* acc2) {
    if (l2 > 0.f) {
        const float mn = fmaxf(m, m2);
        const float ca = __expf(m - mn);    // m==-inf -> 0, kills empty own-partial
        const float cb = __expf(m2 - mn);
        l = l * ca + l2 * cb;
        #pragma unroll
        for (int c = 0; c < CCH; ++c) acc[c] = acc[c] * ca + acc2[c] * cb;
        m = mn;
    }
}

// ---------------- fused causal attention + exact JAX dropout, 16-way split-s ----------------
// Block = (batch b, 32-row q-tile). 8 waves x 2 lane-halves = 16 s-slices of
// 2*(tile+1) iters each. Lane (half, r) owns q-row tile*32+r, s in slice 2w+half.
// Merge: shfl_xor(32) within wave, then 3-round LDS tree (buf = 17.4 KB).
// Grid = 1024 blocks = 4 blocks/CU x 256 CUs, all resident; round-robin CU
// load = tiles {128-x, 96-x, 1+x, 33+x} -> constant sum 258.
__global__ __launch_bounds__(512, 8) void attn_fused(const float* __restrict__ Q,
                                                     const float* __restrict__ K,
                                                     const float* __restrict__ V,
                                                     float* __restrict__ out) {
    __shared__ float buf[4][32][34];            // m, l, acc[32] per (wave-slot, row)

    const int j = blockIdx.x;                   // 0..1023
    const int tile = (j < 512) ? (127 - (j >> 3)) : ((j - 512) >> 3);
    const int b = j & 7;
    const int w = threadIdx.x >> 6;             // wave 0..7
    const int lane = threadIdx.x & 63;
    const int r = lane & 31;                    // row within tile
    const int half = lane >> 5;                 // s-subslice within wave
    const int t = tile * 32 + r;                // this lane's q row

    const size_t rowoff = ((size_t)b * TTN + t) * CCH;
    const float4* qp = reinterpret_cast<const float4*>(Q + rowoff);
    float q[CCH];
    #pragma unroll
    for (int i = 0; i < 8; ++i) {
        float4 t4 = qp[i];
        q[4*i] = t4.x; q[4*i+1] = t4.y; q[4*i+2] = t4.z; q[4*i+3] = t4.w;
    }
    float acc[CCH];
    #pragma unroll
    for (int i = 0; i < CCH; ++i) acc[i] = 0.f;
    float m = -INFINITY, l = 0.f;

    const uint32_t idx_base = ((uint32_t)b << 24) + ((uint32_t)t << 12);
    const float* kbase = K + (size_t)b * TTN * CCH;
    const float* vbase = V + (size_t)b * TTN * CCH;

    const int slice = w * 2 + half;             // 0..15
    const int chunk = 2 * (tile + 1);           // 32*(tile+1) / 16 slices, exact
    const int s0 = slice * chunk;
    const int s1 = s0 + chunk;
    const int mstart = tile * 32;               // s < mstart valid for all lanes
    const int umend = min(s1, mstart);

#define ATT_BODY(VALID_EXPR)                                                   \
    {                                                                          \
        const float4* kp = reinterpret_cast<const float4*>(kbase + (size_t)s * CCH); \
        float kr[CCH];                                                         \
        _Pragma("unroll")                                                      \
        for (int i = 0; i < 8; ++i) {                                          \
            float4 t4 = kp[i];                                                 \
            kr[4*i]=t4.x; kr[4*i+1]=t4.y; kr[4*i+2]=t4.z; kr[4*i+3]=t4.w;      \
        }                                                                      \
        float d0=0.f, d1=0.f, d2=0.f, d3=0.f;                                  \
        _Pragma("unroll")                                                      \
        for (int c = 0; c < CCH; c += 4) {                                     \
            d0 += q[c]   * kr[c];                                              \
            d1 += q[c+1] * kr[c+1];                                            \
            d2 += q[c+2] * kr[c+2];                                            \
            d3 += q[c+3] * kr[c+3];                                            \
        }                                                                      \
        const float score = (d0 + d1) + (d2 + d3);                             \
        const float4* vp = reinterpret_cast<const float4*>(vbase + (size_t)s * CCH); \
        float vr[CCH];                                                         \
        _Pragma("unroll")                                                      \
        for (int i = 0; i < 8; ++i) {                                          \
            float4 t4 = vp[i];                                                 \
            vr[4*i]=t4.x; vr[4*i+1]=t4.y; vr[4*i+2]=t4.z; vr[4*i+3]=t4.w;      \
        }                                                                      \
        const uint32_t bits = mask_bits(idx_base + (uint32_t)s);               \
        const bool keep = (bits >> 9) < KEEP_LT;                               \
        const bool valid = (VALID_EXPR);                                       \
        if (valid && score > m + 8.0f) {        /* deferred-max rescale */     \
            const float corr = __expf(m - score);                              \
            m = score; l *= corr;                                              \
            _Pragma("unroll")                                                  \
            for (int c = 0; c < CCH; ++c) acc[c] *= corr;                      \
        }                                                                      \
        const float p = valid ? __expf(score - m) : 0.f;                       \
        l += p;                                                                \
        const float pk = keep ? p : 0.f;                                       \
        _Pragma("unroll")                                                      \
        for (int c = 0; c < CCH; ++c) acc[c] = fmaf(pk, vr[c], acc[c]);        \
    }

    for (int s = s0; s < umend; ++s) ATT_BODY(true)                    // unmasked bulk
    for (int s = max(s0, mstart); s < s1; ++s) ATT_BODY(s <= t)        // causal tail
#undef ATT_BODY

    // ---- merge the 16 partials per row ----
    // stage 0: combine the two lane-halves of each wave in-register
    {
        float m2 = __shfl_xor(m, 32);
        float l2 = __shfl_xor(l, 32);
        float acc2[CCH];
        #pragma unroll
        for (int c = 0; c < CCH; ++c) acc2[c] = __shfl_xor(acc[c], 32);
        merge_partial(m, l, acc, m2, l2, acc2);
    }
    // stage 1..3: LDS tree 8 -> 4 -> 2 -> 1 wave-partials
    float acc2[CCH]; float m2, l2;
#define PUBLISH(slot)                                                          \
    if (half == 0) {                                                           \
        buf[slot][r][0] = m; buf[slot][r][1] = l;                              \
        _Pragma("unroll")                                                      \
        for (int c = 0; c < CCH; ++c) buf[slot][r][2+c] = acc[c];              \
    }
#define CONSUME(slot)                                                          \
    {                                                                          \
        m2 = buf[slot][r][0]; l2 = buf[slot][r][1];                            \
        _Pragma("unroll")                                                      \
        for (int c = 0; c < CCH; ++c) acc2[c] = buf[slot][r][2+c];             \
        merge_partial(m, l, acc, m2, l2, acc2);                                \
    }
    if (w >= 4) PUBLISH(w - 4)
    __syncthreads();
    if (w < 4) CONSUME(w)
    __syncthreads();
    if (w == 2 || w == 3) PUBLISH(w - 2)
    __syncthreads();
    if (w < 2) CONSUME(w)
    __syncthreads();
    if (w == 1) PUBLISH(0)
    __syncthreads();
    if (w == 0) {
        CONSUME(0)
        if (half == 0) {
            const float inv = 1.0f / (0.8f * l);
            float4* op = reinterpret_cast<float4*>(out + rowoff);
            #pragma unroll
            for (int i = 0; i < 8; ++i)
                op[i] = make_float4(acc[4*i]*inv, acc[4*i+1]*inv,
                                    acc[4*i+2]*inv, acc[4*i+3]*inv);
        }
    }
#undef PUBLISH
#undef CONSUME
}

extern "C" void kernel_launch(void* const* d_in, const int* in_sizes, int n_in,
                              void* d_out, int out_size, void* d_ws, size_t ws_size,
                              hipStream_t stream) {
    const float* x  = (const float*)d_in[0];
    const float* Wq = (const float*)d_in[1];
    const float* Wk = (const float*)d_in[2];
    const float* Wv = (const float*)d_in[3];
    float* outp = (float*)d_out;

    float* Qw = (float*)d_ws;
    float* Kw = Qw + (size_t)BB * TTN * CCH;
    float* Vw = Kw + (size_t)BB * TTN * CCH;

    proj_qkv<<<(BB * TTN) / 256, 256, 0, stream>>>(x, Wq, Wk, Wv, Qw, Kw, Vw);
    attn_fused<<<1024, 512, 0, stream>>>(Qw, Kw, Vw, outp);
}

// Round 4
// 1945.817 us; speedup vs baseline: 1.5274x; 1.5274x over previous
//
#include <hip/hip_runtime.h>
#include <stdint.h>

#define BB 8
#define TTN 4096
#define CCH 32
#define WIN 128
#define KEEP_LT 6710887u     // keep iff (bits>>9) < this  <=> uniform < 0.8f

__device__ __forceinline__ uint32_t rotl32(uint32_t x, int r) {
    return (x << r) | (x >> (32 - r));
}

// threefry2x32, 20 rounds, key fixed to (0, 42) == jax.random.key(42)
__device__ __forceinline__ void threefry2x32_k042(uint32_t x0, uint32_t x1,
                                                  uint32_t& o0, uint32_t& o1) {
    const uint32_t k0 = 0u, k1 = 42u;
    const uint32_t k2 = 0u ^ 42u ^ 0x1BD11BDAu;
    x0 += k0; x1 += k1;
#define TFR(r) { x0 += x1; x1 = rotl32(x1, (r)); x1 ^= x0; }
    TFR(13) TFR(15) TFR(26) TFR(6)
    x0 += k1; x1 += k2 + 1u;
    TFR(17) TFR(29) TFR(16) TFR(24)
    x0 += k2; x1 += k0 + 2u;
    TFR(13) TFR(15) TFR(26) TFR(6)
    x0 += k0; x1 += k1 + 3u;
    TFR(17) TFR(29) TFR(16) TFR(24)
    x0 += k1; x1 += k2 + 4u;
    TFR(13) TFR(15) TFR(26) TFR(6)
    x0 += k2; x1 += k0 + 5u;
#undef TFR
    o0 = x0; o1 = x1;
}

// partitionable threefry: bits(i) = o0^o1 of threefry(key42, (0, i))
__device__ __forceinline__ uint32_t mask_bits(uint32_t idx) {
    uint32_t o0, o1; threefry2x32_k042(0u, idx, o0, o1); return o0 ^ o1;
}

// ---------------- projections: q = (x @ Wq^T) * 1/sqrt(32), k, v ----------------
__global__ __launch_bounds__(256) void proj_qkv(const float* __restrict__ x,
                                                const float* __restrict__ Wq,
                                                const float* __restrict__ Wk,
                                                const float* __restrict__ Wv,
                                                float* __restrict__ Q,
                                                float* __restrict__ K,
                                                float* __restrict__ V) {
    __shared__ float sW[3][CCH * CCH];
    const int tid = threadIdx.x;
    for (int i = tid; i < CCH * CCH; i += 256) {
        sW[0][i] = Wq[i]; sW[1][i] = Wk[i]; sW[2][i] = Wv[i];
    }
    __syncthreads();
    const int row = blockIdx.x * 256 + tid;     // b*T + t
    const float4* xp = reinterpret_cast<const float4*>(x + (size_t)row * CCH);
    float xr[CCH];
    #pragma unroll
    for (int i = 0; i < 8; ++i) {
        float4 t4 = xp[i];
        xr[4*i] = t4.x; xr[4*i+1] = t4.y; xr[4*i+2] = t4.z; xr[4*i+3] = t4.w;
    }
    const float scale = 0.17677669529663687f;   // 1/sqrt(32)
    for (int mtx = 0; mtx < 3; ++mtx) {
        float* op_base = (mtx == 0) ? Q : ((mtx == 1) ? K : V);
        float o[CCH];
        #pragma unroll
        for (int d = 0; d < CCH; ++d) {
            float s0 = 0.f, s1 = 0.f, s2 = 0.f, s3 = 0.f;
            #pragma unroll
            for (int c = 0; c < CCH; c += 4) {
                s0 += xr[c]   * sW[mtx][d*CCH + c];
                s1 += xr[c+1] * sW[mtx][d*CCH + c+1];
                s2 += xr[c+2] * sW[mtx][d*CCH + c+2];
                s3 += xr[c+3] * sW[mtx][d*CCH + c+3];
            }
            o[d] = (s0 + s1) + (s2 + s3);
            if (mtx == 0) o[d] *= scale;
        }
        float4* op = reinterpret_cast<float4*>(op_base + (size_t)row * CCH);
        #pragma unroll
        for (int i = 0; i < 8; ++i)
            op[i] = make_float4(o[4*i], o[4*i+1], o[4*i+2], o[4*i+3]);
    }
}

// merge partial (m2,l2,acc2) into (m,l,acc); no-op when l2==0 (avoids inf-inf NaN)
__device__ __forceinline__ void merge_partial(float& m, float& l, float* acc,
                                              float m2, float l2, const float* acc2) {
    if (l2 > 0.f) {
        const float mn = fmaxf(m, m2);
        const float ca = __expf(m - mn);
        const float cb = __expf(m2 - mn);
        l = l * ca + l2 * cb;
        #pragma unroll
        for (int c = 0; c < CCH; ++c) acc[c] = acc[c] * ca + acc2[c] * cb;
        m = mn;
    }
}

// ---------------- fused causal attention, LDS-staged K/V windows ----------------
// Block = (batch b, 32-row q-tile); b = blockIdx&7 -> per-XCD K/V L2 locality.
// 8 waves x 2 halves = 16 s-slices of 8 within each 128-wide staged window.
// Staging: T14 async split (issue loads -> compute -> ds_write -> barrier),
// double-buffered: K0|K1|V0|V1 @ 16KB each = 64KB LDS. Merge tree aliases LDS.
__global__ __launch_bounds__(512, 4) void attn_fused(const float* __restrict__ Q,
                                                     const float* __restrict__ K,
                                                     const float* __restrict__ V,
                                                     float* __restrict__ out) {
    __shared__ __align__(16) float smem[16384];   // 64 KB

    const int j = blockIdx.x;                   // 0..1023
    const int b = j & 7;                        // XCD-local batch
    const int u = j >> 3;                       // 0..127
    const int x = u >> 1;                       // 0..63
    const int tile = (u & 1) ? x : (127 - x);   // interleave big/small for balance

    const int w = threadIdx.x >> 6;             // wave 0..7
    const int lane = threadIdx.x & 63;
    const int r = lane & 31;                    // row within tile
    const int half = lane >> 5;
    const int slice = 2 * w + half;             // 0..15
    const int sl8 = slice * 8;                  // slice's local s offset
    const int t = tile * 32 + r;

    const size_t rowoff = ((size_t)b * TTN + t) * CCH;
    const float4* qp = reinterpret_cast<const float4*>(Q + rowoff);
    float q[CCH];
    #pragma unroll
    for (int i = 0; i < 8; ++i) {
        float4 t4 = qp[i];
        q[4*i] = t4.x; q[4*i+1] = t4.y; q[4*i+2] = t4.z; q[4*i+3] = t4.w;
    }
    float acc[CCH];
    #pragma unroll
    for (int i = 0; i < CCH; ++i) acc[i] = 0.f;
    float m = -INFINITY, l = 0.f;

    const uint32_t idx_base = ((uint32_t)b << 24) + ((uint32_t)t << 12);
    const float* Kb = K + (size_t)b * TTN * CCH;
    const float* Vb = V + (size_t)b * TTN * CCH;

    const int nwin = (32 * tile + 159) >> 7;    // windows to cover s <= 32*tile+31
    const int diagmax = 32 * (tile & 3) + 31;   // diagonal's local s in tail window

    // staging registers (4 x 16B per wave per window: 2 K-chunks + 2 V-chunks)
    float4 sg0, sg1, sg2, sg3;
    const int c0 = w * 256 + lane * 4;          // chunk float offsets in 4096-float buf
    const int c1 = (w + 8) * 256 + lane * 4;

#define ISSUE_LOADS(S0)                                                        \
    {                                                                          \
        const float* gk = Kb + (size_t)(S0) * CCH;                             \
        const float* gv = Vb + (size_t)(S0) * CCH;                             \
        sg0 = *reinterpret_cast<const float4*>(gk + c0);                       \
        sg1 = *reinterpret_cast<const float4*>(gk + c1);                       \
        sg2 = *reinterpret_cast<const float4*>(gv + c0);                       \
        sg3 = *reinterpret_cast<const float4*>(gv + c1);                       \
    }
#define WRITE_LDS(DBUF)                                                        \
    {                                                                          \
        float* dk = smem + (DBUF) * 4096;                                      \
        float* dv = smem + 8192 + (DBUF) * 4096;                               \
        *reinterpret_cast<float4*>(dk + c0) = sg0;                             \
        *reinterpret_cast<float4*>(dk + c1) = sg1;                             \
        *reinterpret_cast<float4*>(dv + c0) = sg2;                             \
        *reinterpret_cast<float4*>(dv + c1) = sg3;                             \
    }

    ISSUE_LOADS(0)
    WRITE_LDS(0)
    __syncthreads();

    int buf = 0;
    for (int win = 0; win < nwin; ++win) {
        const int s0 = win << 7;
        const bool last = (win == nwin - 1);
        if (!last) ISSUE_LOADS(s0 + WIN)        // prefetch next window (hidden under compute)

        if (!last || sl8 <= diagmax) {          // skip slices fully beyond diagonal
            const int kbase = buf * 4096 + sl8 * 32;   // float index of slice row 0 (K)
            #pragma unroll
            for (int k = 0; k < 8; ++k) {
                const int row = kbase + k * 32;
                float kr[CCH];
                #pragma unroll
                for (int i = 0; i < 8; ++i) {
                    float4 t4 = *reinterpret_cast<const float4*>(&smem[row + 4*i]);
                    kr[4*i]=t4.x; kr[4*i+1]=t4.y; kr[4*i+2]=t4.z; kr[4*i+3]=t4.w;
                }
                float d0=0.f, d1=0.f, d2=0.f, d3=0.f;
                #pragma unroll
                for (int c = 0; c < CCH; c += 4) {
                    d0 += q[c]   * kr[c];
                    d1 += q[c+1] * kr[c+1];
                    d2 += q[c+2] * kr[c+2];
                    d3 += q[c+3] * kr[c+3];
                }
                const float score = (d0 + d1) + (d2 + d3);

                const int s = s0 + sl8 + k;
                const uint32_t bits = mask_bits(idx_base + (uint32_t)s);
                const bool keep = (bits >> 9) < KEEP_LT;
                const bool valid = !last || (s <= t);

                float vr[CCH];
                #pragma unroll
                for (int i = 0; i < 8; ++i) {
                    float4 t4 = *reinterpret_cast<const float4*>(&smem[8192 + row + 4*i]);
                    vr[4*i]=t4.x; vr[4*i+1]=t4.y; vr[4*i+2]=t4.z; vr[4*i+3]=t4.w;
                }

                if (valid && score > m + 8.0f) {       // deferred-max rescale
                    const float corr = __expf(m - score);
                    m = score; l *= corr;
                    #pragma unroll
                    for (int c = 0; c < CCH; ++c) acc[c] *= corr;
                }
                const float p = valid ? __expf(score - m) : 0.f;
                l += p;
                const float pk = keep ? p : 0.f;
                #pragma unroll
                for (int c = 0; c < CCH; ++c) acc[c] = fmaf(pk, vr[c], acc[c]);
            }
        }

        if (!last) WRITE_LDS(buf ^ 1)
        __syncthreads();
        buf ^= 1;
    }
#undef ISSUE_LOADS
#undef WRITE_LDS

    // ---- merge the 16 partials per row (aliases staging LDS; barrier above) ----
    {
        float m2 = __shfl_xor(m, 32);
        float l2 = __shfl_xor(l, 32);
        float acc2[CCH];
        #pragma unroll
        for (int c = 0; c < CCH; ++c) acc2[c] = __shfl_xor(acc[c], 32);
        merge_partial(m, l, acc, m2, l2, acc2);
    }
    float* mbuf = smem;                         // [4][32][34] floats = 17408 B
    float acc2[CCH]; float m2, l2;
#define PUBLISH(slot)                                                          \
    if (half == 0) {                                                           \
        float* pb = mbuf + ((slot) * 32 + r) * 34;                             \
        pb[0] = m; pb[1] = l;                                                  \
        _Pragma("unroll")                                                      \
        for (int c = 0; c < CCH; ++c) pb[2+c] = acc[c];                        \
    }
#define CONSUME(slot)                                                          \
    {                                                                          \
        const float* pb = mbuf + ((slot) * 32 + r) * 34;                       \
        m2 = pb[0]; l2 = pb[1];                                                \
        _Pragma("unroll")                                                      \
        for (int c = 0; c < CCH; ++c) acc2[c] = pb[2+c];                       \
        merge_partial(m, l, acc, m2, l2, acc2);                                \
    }
    if (w >= 4) PUBLISH(w - 4)
    __syncthreads();
    if (w < 4) CONSUME(w)
    __syncthreads();
    if (w == 2 || w == 3) PUBLISH(w - 2)
    __syncthreads();
    if (w < 2) CONSUME(w)
    __syncthreads();
    if (w == 1) PUBLISH(0)
    __syncthreads();
    if (w == 0) {
        CONSUME(0)
        if (half == 0) {
            const float inv = 1.0f / (0.8f * l);
            float4* op = reinterpret_cast<float4*>(out + rowoff);
            #pragma unroll
            for (int i = 0; i < 8; ++i)
                op[i] = make_float4(acc[4*i]*inv, acc[4*i+1]*inv,
                                    acc[4*i+2]*inv, acc[4*i+3]*inv);
        }
    }
#undef PUBLISH
#undef CONSUME
}

extern "C" void kernel_launch(void* const* d_in, const int* in_sizes, int n_in,
                              void* d_out, int out_size, void* d_ws, size_t ws_size,
                              hipStream_t stream) {
    const float* x  = (const float*)d_in[0];
    const float* Wq = (const float*)d_in[1];
    const float* Wk = (const float*)d_in[2];
    const float* Wv = (const float*)d_in[3];
    float* outp = (float*)d_out;

    float* Qw = (float*)d_ws;
    float* Kw = Qw + (size_t)BB * TTN * CCH;
    float* Vw = Kw + (size_t)BB * TTN * CCH;

    proj_qkv<<<(BB * TTN) / 256, 256, 0, stream>>>(x, Wq, Wk, Wv, Qw, Kw, Vw);
    attn_fused<<<1024, 512, 0, stream>>>(Qw, Kw, Vw, outp);
}

// Round 5
// 405.667 us; speedup vs baseline: 7.3262x; 4.7966x over previous
//
#include <hip/hip_runtime.h>
#include <stdint.h>

#define BB 8
#define TTN 4096
#define CCH 32
#define WIN 128
#define KEEP_LT 6710887u     // keep iff (bits>>9) < this  <=> uniform < 0.8f

__device__ __forceinline__ uint32_t rotl32(uint32_t x, int r) {
    return (x << r) | (x >> (32 - r));
}

// threefry2x32, 20 rounds, key fixed to (0, 42) == jax.random.key(42)
__device__ __forceinline__ void threefry2x32_k042(uint32_t x0, uint32_t x1,
                                                  uint32_t& o0, uint32_t& o1) {
    const uint32_t k0 = 0u, k1 = 42u;
    const uint32_t k2 = 0u ^ 42u ^ 0x1BD11BDAu;
    x0 += k0; x1 += k1;
#define TFR(r) { x0 += x1; x1 = rotl32(x1, (r)); x1 ^= x0; }
    TFR(13) TFR(15) TFR(26) TFR(6)
    x0 += k1; x1 += k2 + 1u;
    TFR(17) TFR(29) TFR(16) TFR(24)
    x0 += k2; x1 += k0 + 2u;
    TFR(13) TFR(15) TFR(26) TFR(6)
    x0 += k0; x1 += k1 + 3u;
    TFR(17) TFR(29) TFR(16) TFR(24)
    x0 += k1; x1 += k2 + 4u;
    TFR(13) TFR(15) TFR(26) TFR(6)
    x0 += k2; x1 += k0 + 5u;
#undef TFR
    o0 = x0; o1 = x1;
}

// partitionable threefry: bits(i) = o0^o1 of threefry(key42, (0, i))
__device__ __forceinline__ uint32_t mask_bits(uint32_t idx) {
    uint32_t o0, o1; threefry2x32_k042(0u, idx, o0, o1); return o0 ^ o1;
}

// ---------------- projections: q = (x @ Wq^T) * 1/sqrt(32), k, v ----------------
__global__ __launch_bounds__(256) void proj_qkv(const float* __restrict__ x,
                                                const float* __restrict__ Wq,
                                                const float* __restrict__ Wk,
                                                const float* __restrict__ Wv,
                                                float* __restrict__ Q,
                                                float* __restrict__ K,
                                                float* __restrict__ V) {
    __shared__ float sW[3][CCH * CCH];
    const int tid = threadIdx.x;
    for (int i = tid; i < CCH * CCH; i += 256) {
        sW[0][i] = Wq[i]; sW[1][i] = Wk[i]; sW[2][i] = Wv[i];
    }
    __syncthreads();
    const int row = blockIdx.x * 256 + tid;     // b*T + t
    const float4* xp = reinterpret_cast<const float4*>(x + (size_t)row * CCH);
    float xr[CCH];
    #pragma unroll
    for (int i = 0; i < 8; ++i) {
        float4 t4 = xp[i];
        xr[4*i] = t4.x; xr[4*i+1] = t4.y; xr[4*i+2] = t4.z; xr[4*i+3] = t4.w;
    }
    const float scale = 0.17677669529663687f;   // 1/sqrt(32)
    for (int mtx = 0; mtx < 3; ++mtx) {
        float* op_base = (mtx == 0) ? Q : ((mtx == 1) ? K : V);
        float o[CCH];
        #pragma unroll
        for (int d = 0; d < CCH; ++d) {
            float s0 = 0.f, s1 = 0.f, s2 = 0.f, s3 = 0.f;
            #pragma unroll
            for (int c = 0; c < CCH; c += 4) {
                s0 += xr[c]   * sW[mtx][d*CCH + c];
                s1 += xr[c+1] * sW[mtx][d*CCH + c+1];
                s2 += xr[c+2] * sW[mtx][d*CCH + c+2];
                s3 += xr[c+3] * sW[mtx][d*CCH + c+3];
            }
            o[d] = (s0 + s1) + (s2 + s3);
            if (mtx == 0) o[d] *= scale;
        }
        float4* op = reinterpret_cast<float4*>(op_base + (size_t)row * CCH);
        #pragma unroll
        for (int i = 0; i < 8; ++i)
            op[i] = make_float4(o[4*i], o[4*i+1], o[4*i+2], o[4*i+3]);
    }
}

// merge partial (m2,l2,acc2) into (m,l,acc); no-op when l2==0 (avoids inf-inf NaN)
__device__ __forceinline__ void merge_partial(float& m, float& l, float* acc,
                                              float m2, float l2, const float* acc2) {
    if (l2 > 0.f) {
        const float mn = fmaxf(m, m2);
        const float ca = __expf(m - mn);
        const float cb = __expf(m2 - mn);
        l = l * ca + l2 * cb;
        #pragma unroll
        for (int c = 0; c < CCH; ++c) acc[c] = acc[c] * ca + acc2[c] * cb;
        m = mn;
    }
}

// ---------------- fused causal attention, LDS-staged K/V windows ----------------
// Block = (batch b, 32-row q-tile); b = blockIdx&7 -> per-XCD K/V L2 locality.
// 8 waves x 2 halves = 16 s-slices of 8 within each 128-wide staged window.
// Staging: async split (issue loads -> compute -> ds_write -> barrier), double-
// buffered 64KB LDS. Inner loop is chunk-fused (NO kr[]/vr[] register arrays):
// peak live ~105 VGPR -> fits the 128 cap of __launch_bounds__(512,4), no spill.
__global__ __launch_bounds__(512, 4) void attn_fused(const float* __restrict__ Q,
                                                     const float* __restrict__ K,
                                                     const float* __restrict__ V,
                                                     float* __restrict__ out) {
    __shared__ __align__(16) float smem[16384];   // 64 KB

    const int j = blockIdx.x;                   // 0..1023
    const int b = j & 7;                        // XCD-local batch
    const int u = j >> 3;                       // 0..127
    const int x = u >> 1;                       // 0..63
    const int tile = (u & 1) ? x : (127 - x);   // interleave big/small for balance

    const int w = threadIdx.x >> 6;             // wave 0..7
    const int lane = threadIdx.x & 63;
    const int r = lane & 31;                    // row within tile
    const int half = lane >> 5;
    const int slice = 2 * w + half;             // 0..15
    const int sl8 = slice * 8;                  // slice's local s offset
    const int t = tile * 32 + r;

    const size_t rowoff = ((size_t)b * TTN + t) * CCH;
    const float4* qp = reinterpret_cast<const float4*>(Q + rowoff);
    float q[CCH];
    #pragma unroll
    for (int i = 0; i < 8; ++i) {
        float4 t4 = qp[i];
        q[4*i] = t4.x; q[4*i+1] = t4.y; q[4*i+2] = t4.z; q[4*i+3] = t4.w;
    }
    float acc[CCH];
    #pragma unroll
    for (int i = 0; i < CCH; ++i) acc[i] = 0.f;
    float m = -INFINITY, l = 0.f;

    const uint32_t idx_base = ((uint32_t)b << 24) + ((uint32_t)t << 12);
    const float* Kb = K + (size_t)b * TTN * CCH;
    const float* Vb = V + (size_t)b * TTN * CCH;

    const int nwin = (32 * tile + 159) >> 7;    // windows to cover s <= 32*tile+31
    const int diagmax = 32 * (tile & 3) + 31;   // diagonal's local s in tail window

    // staging registers (4 x 16B per wave per window: 2 K-chunks + 2 V-chunks)
    float4 sg0, sg1, sg2, sg3;
    const int c0 = w * 256 + lane * 4;          // chunk float offsets in 4096-float buf
    const int c1 = (w + 8) * 256 + lane * 4;

#define ISSUE_LOADS(S0)                                                        \
    {                                                                          \
        const float* gk = Kb + (size_t)(S0) * CCH;                             \
        const float* gv = Vb + (size_t)(S0) * CCH;                             \
        sg0 = *reinterpret_cast<const float4*>(gk + c0);                       \
        sg1 = *reinterpret_cast<const float4*>(gk + c1);                       \
        sg2 = *reinterpret_cast<const float4*>(gv + c0);                       \
        sg3 = *reinterpret_cast<const float4*>(gv + c1);                       \
    }
#define WRITE_LDS(DBUF)                                                        \
    {                                                                          \
        float* dk = smem + (DBUF) * 4096;                                      \
        float* dv = smem + 8192 + (DBUF) * 4096;                               \
        *reinterpret_cast<float4*>(dk + c0) = sg0;                             \
        *reinterpret_cast<float4*>(dk + c1) = sg1;                             \
        *reinterpret_cast<float4*>(dv + c0) = sg2;                             \
        *reinterpret_cast<float4*>(dv + c1) = sg3;                             \
    }

    ISSUE_LOADS(0)
    WRITE_LDS(0)
    __syncthreads();

    int buf = 0;
    for (int win = 0; win < nwin; ++win) {
        const int s0 = win << 7;
        const bool last = (win == nwin - 1);
        if (!last) ISSUE_LOADS(s0 + WIN)        // prefetch next window (hidden under compute)

        if (!last || sl8 <= diagmax) {          // skip slices fully beyond diagonal
            const int kbase = buf * 4096 + sl8 * 32;   // float index of slice row 0 (K)
            #pragma unroll 1
            for (int k = 0; k < 8; ++k) {
                const float* krow = &smem[kbase + k * 32];
                // ---- dot(q, K_row) fused in 4-float chunks (no kr[] array) ----
                float d0 = 0.f, d1 = 0.f, d2 = 0.f, d3 = 0.f;
                #pragma unroll
                for (int i = 0; i < 8; ++i) {
                    float4 kc = *reinterpret_cast<const float4*>(krow + 4 * i);
                    d0 = fmaf(q[4*i],   kc.x, d0);
                    d1 = fmaf(q[4*i+1], kc.y, d1);
                    d2 = fmaf(q[4*i+2], kc.z, d2);
                    d3 = fmaf(q[4*i+3], kc.w, d3);
                }
                const float score = (d0 + d1) + (d2 + d3);

                const int s = s0 + sl8 + k;
                const uint32_t bits = mask_bits(idx_base + (uint32_t)s);
                const bool keep = (bits >> 9) < KEEP_LT;
                const bool valid = !last || (s <= t);

                if (valid && score > m + 8.0f) {       // deferred-max rescale (rare)
                    const float corr = __expf(m - score);
                    m = score; l *= corr;
                    #pragma unroll
                    for (int c = 0; c < CCH; ++c) acc[c] *= corr;
                }
                const float p = valid ? __expf(score - m) : 0.f;
                l += p;
                const float pk = keep ? p : 0.f;

                // ---- acc += pk * V_row fused in 4-float chunks (no vr[] array) ----
                const float* vrow = &smem[8192 + kbase + k * 32];
                #pragma unroll
                for (int i = 0; i < 8; ++i) {
                    float4 vc = *reinterpret_cast<const float4*>(vrow + 4 * i);
                    acc[4*i]   = fmaf(pk, vc.x, acc[4*i]);
                    acc[4*i+1] = fmaf(pk, vc.y, acc[4*i+1]);
                    acc[4*i+2] = fmaf(pk, vc.z, acc[4*i+2]);
                    acc[4*i+3] = fmaf(pk, vc.w, acc[4*i+3]);
                }
            }
        }

        if (!last) WRITE_LDS(buf ^ 1)
        __syncthreads();
        buf ^= 1;
    }
#undef ISSUE_LOADS
#undef WRITE_LDS

    // ---- merge the 16 partials per row (aliases staging LDS; barrier above) ----
    {
        float m2 = __shfl_xor(m, 32);
        float l2 = __shfl_xor(l, 32);
        float acc2[CCH];
        #pragma unroll
        for (int c = 0; c < CCH; ++c) acc2[c] = __shfl_xor(acc[c], 32);
        merge_partial(m, l, acc, m2, l2, acc2);
    }
    float* mbuf = smem;                         // [4][32][34] floats = 17408 B
    float acc2[CCH]; float m2, l2;
#define PUBLISH(slot)                                                          \
    if (half == 0) {                                                           \
        float* pb = mbuf + ((slot) * 32 + r) * 34;                             \
        pb[0] = m; pb[1] = l;                                                  \
        _Pragma("unroll")                                                      \
        for (int c = 0; c < CCH; ++c) pb[2+c] = acc[c];                        \
    }
#define CONSUME(slot)                                                          \
    {                                                                          \
        const float* pb = mbuf + ((slot) * 32 + r) * 34;                       \
        m2 = pb[0]; l2 = pb[1];                                                \
        _Pragma("unroll")                                                      \
        for (int c = 0; c < CCH; ++c) acc2[c] = pb[2+c];                       \
        merge_partial(m, l, acc, m2, l2, acc2);                                \
    }
    if (w >= 4) PUBLISH(w - 4)
    __syncthreads();
    if (w < 4) CONSUME(w)
    __syncthreads();
    if (w == 2 || w == 3) PUBLISH(w - 2)
    __syncthreads();
    if (w < 2) CONSUME(w)
    __syncthreads();
    if (w == 1) PUBLISH(0)
    __syncthreads();
    if (w == 0) {
        CONSUME(0)
        if (half == 0) {
            const float inv = 1.0f / (0.8f * l);
            float4* op = reinterpret_cast<float4*>(out + rowoff);
            #pragma unroll
            for (int i = 0; i < 8; ++i)
                op[i] = make_float4(acc[4*i]*inv, acc[4*i+1]*inv,
                                    acc[4*i+2]*inv, acc[4*i+3]*inv);
        }
    }
#undef PUBLISH
#undef CONSUME
}

extern "C" void kernel_launch(void* const* d_in, const int* in_sizes, int n_in,
                              void* d_out, int out_size, void* d_ws, size_t ws_size,
                              hipStream_t stream) {
    const float* x  = (const float*)d_in[0];
    const float* Wq = (const float*)d_in[1];
    const float* Wk = (const float*)d_in[2];
    const float* Wv = (const float*)d_in[3];
    float* outp = (float*)d_out;

    float* Qw = (float*)d_ws;
    float* Kw = Qw + (size_t)BB * TTN * CCH;
    float* Vw = Kw + (size_t)BB * TTN * CCH;

    proj_qkv<<<(BB * TTN) / 256, 256, 0, stream>>>(x, Wq, Wk, Wv, Qw, Kw, Vw);
    attn_fused<<<1024, 512, 0, stream>>>(Qw, Kw, Vw, outp);
}